// Round 2
// baseline (12270.909 us; speedup 1.0000x reference)
//
#include <hip/hip_runtime.h>
#include <math.h>

#define TAGS 9
#define NWG 256

static __device__ __forceinline__ float sigmoidf_(float x) {
  return 1.0f / (1.0f + expf(-x));
}

// ---------------- embedding gather: seq[tb][e] = table[x[tb]][e] ----------------
__global__ void k_gather(const int* __restrict__ x, const float* __restrict__ table,
                         float* __restrict__ seq) {
  int tid = blockIdx.x * 256 + threadIdx.x;   // 16384*128 float4s
  int row = tid >> 7;
  int e4 = tid & 127;
  int idx = x[row];
  const float4* src = (const float4*)(table + (size_t)idx * 512);
  float4* dst = (float4*)(seq + (size_t)row * 512);
  dst[e4] = src[e4];
}

// ---------------- gates GEMM, transposed output ----------------
// gatesT[t][m][b] = sum_k A[m][k] * B[t*64+b][k] + bias1[m] + bias2[m]
// A = w_ih layer slice [2048][512]; B = seq [16384][512]. M=2048 (grid.y=16), N=16384 (grid.x=128)
__global__ __launch_bounds__(256, 2)
void k_gemm_gates(const float* __restrict__ A, const float* __restrict__ B,
                  const float* __restrict__ bias1, const float* __restrict__ bias2,
                  float* __restrict__ gatesT) {
  __shared__ float As[16][132];
  __shared__ float Bs[16][132];
  int tid = threadIdx.x;
  int tx = tid & 15, ty = tid >> 4;
  int n0 = blockIdx.x * 128, m0 = blockIdx.y * 128;
  int lr = tid >> 2;               // 0..63
  int lk = (tid & 3) * 4;          // 0,4,8,12
  float acc[8][8];
#pragma unroll
  for (int i = 0; i < 8; i++)
#pragma unroll
    for (int j = 0; j < 8; j++) acc[i][j] = 0.f;
  const float* Ab = A + (size_t)m0 * 512;
  const float* Bb = B + (size_t)n0 * 512;
  for (int k0 = 0; k0 < 512; k0 += 16) {
    float4 a0 = *(const float4*)&Ab[(size_t)lr * 512 + k0 + lk];
    float4 a1 = *(const float4*)&Ab[(size_t)(lr + 64) * 512 + k0 + lk];
    float4 w0 = *(const float4*)&Bb[(size_t)lr * 512 + k0 + lk];
    float4 w1 = *(const float4*)&Bb[(size_t)(lr + 64) * 512 + k0 + lk];
    __syncthreads();
    As[lk + 0][lr] = a0.x; As[lk + 1][lr] = a0.y; As[lk + 2][lr] = a0.z; As[lk + 3][lr] = a0.w;
    As[lk + 0][lr + 64] = a1.x; As[lk + 1][lr + 64] = a1.y; As[lk + 2][lr + 64] = a1.z; As[lk + 3][lr + 64] = a1.w;
    Bs[lk + 0][lr] = w0.x; Bs[lk + 1][lr] = w0.y; Bs[lk + 2][lr] = w0.z; Bs[lk + 3][lr] = w0.w;
    Bs[lk + 0][lr + 64] = w1.x; Bs[lk + 1][lr + 64] = w1.y; Bs[lk + 2][lr + 64] = w1.z; Bs[lk + 3][lr + 64] = w1.w;
    __syncthreads();
#pragma unroll
    for (int kk = 0; kk < 16; kk++) {
      float4 av0 = *(const float4*)&As[kk][ty * 4];
      float4 av1 = *(const float4*)&As[kk][ty * 4 + 64];
      float4 bv0 = *(const float4*)&Bs[kk][tx * 4];
      float4 bv1 = *(const float4*)&Bs[kk][tx * 4 + 64];
      float am[8] = {av0.x, av0.y, av0.z, av0.w, av1.x, av1.y, av1.z, av1.w};
      float bn[8] = {bv0.x, bv0.y, bv0.z, bv0.w, bv1.x, bv1.y, bv1.z, bv1.w};
#pragma unroll
      for (int i = 0; i < 8; i++)
#pragma unroll
        for (int j = 0; j < 8; j++) acc[i][j] += am[i] * bn[j];
    }
  }
  // epilogue: write gatesT[t][m][b], t = n>>6, b = n&63 (n0 is a multiple of 128)
  int t0 = n0 >> 6;
#pragma unroll
  for (int i = 0; i < 8; i++) {
    int m = m0 + ((i < 4) ? (ty * 4 + i) : (64 + ty * 4 + (i - 4)));
    float bs = bias1[m] + bias2[m];
    float4 o0 = {acc[i][0] + bs, acc[i][1] + bs, acc[i][2] + bs, acc[i][3] + bs};
    float4 o1 = {acc[i][4] + bs, acc[i][5] + bs, acc[i][6] + bs, acc[i][7] + bs};
    *(float4*)&gatesT[((size_t)t0 * 2048 + m) * 64 + tx * 4] = o0;
    *(float4*)&gatesT[((size_t)(t0 + 1) * 2048 + m) * 64 + tx * 4] = o1;
  }
}

// ---------------- persistent cooperative LSTM layer ----------------
// 256 WGs x 512 threads, 1 WG/CU (88KB LDS). WG = (dir d, unit-group ug of 2 units).
// LDS-resident weights (8 gate rows x 256). Per step: stage h (64KB) -> GEMV -> pointwise
// (threads ks<2) -> write h to global double-buffer -> device barrier.
__global__ __launch_bounds__(512)
void k_lstm_rec(const float* __restrict__ gatesT,   // [256][2048][64]
                const float* __restrict__ whh,      // [2][1024][256] layer slice
                float* __restrict__ seq_out,        // [16384][512]
                float* __restrict__ hbuf,           // [2][2][64][256]
                int* __restrict__ gbar,             // {cnt, gen}
                int gen_base) {
  __shared__ float h_s[256 * 64];   // phys: [k][ b ^ ((k>>2)&63) ]  (conflict-free R/W)
  __shared__ float w_s[8][256];     // local row = gate*2 + uo
  __shared__ float g_p[64 * 64];    // partials [ks*8+row][b]
  int wg = blockIdx.x, tid = threadIdx.x;
  int d = wg & 1, ug = wg >> 1;     // ug 0..127
  int b = tid & 63, ks = tid >> 6;  // ks 0..7
  // stage weights once: row rr = ks (gate = ks>>1, uo = ks&1), lane b covers 4 k
  {
    int gate = ks >> 1, uo = ks & 1;
    const float* src = whh + ((size_t)d * 1024 + gate * 256 + ug * 2 + uo) * 256;
    *(float4*)&w_s[ks][b * 4] = *(const float4*)&src[b * 4];
  }
  // zero h phase-0 (32768 floats over 256 WGs)
  if (tid < 128) hbuf[(size_t)wg * 128 + tid] = 0.f;
  int mygen = gen_base;
  float c = 0.f;

  auto BAR = [&]() {
    __syncthreads();
    if (tid == 0) {
      mygen++;
      int prev = __hip_atomic_fetch_add(&gbar[0], 1, __ATOMIC_RELEASE, __HIP_MEMORY_SCOPE_AGENT);
      if (prev == NWG - 1) {
        __hip_atomic_store(&gbar[0], 0, __ATOMIC_RELAXED, __HIP_MEMORY_SCOPE_AGENT);
        __hip_atomic_store(&gbar[1], mygen, __ATOMIC_RELEASE, __HIP_MEMORY_SCOPE_AGENT);
      } else {
        while (__hip_atomic_load(&gbar[1], __ATOMIC_RELAXED, __HIP_MEMORY_SCOPE_AGENT) < mygen)
          __builtin_amdgcn_s_sleep(2);
      }
      __builtin_amdgcn_fence(__ATOMIC_ACQUIRE, "agent");
    }
    __syncthreads();
  };

  BAR();  // zeros + weights visible everywhere

  for (int tt = 0; tt < 256; tt++) {
    int t = d ? (255 - tt) : tt;
    // prefetch this step's input-gate values (threads ks<2 own pointwise for uo=ks)
    float gin0 = 0.f, gin1 = 0.f, gin2 = 0.f, gin3 = 0.f;
    if (ks < 2) {
      int u = ug * 2 + ks;
      const float* gp = gatesT + ((size_t)t * 2048 + d * 1024 + u) * 64 + b;
      gin0 = gp[0];
      gin1 = gp[(size_t)256 * 64];
      gin2 = gp[(size_t)512 * 64];
      gin3 = gp[(size_t)768 * 64];
    }
    // stage h[d] (64 KB) global -> LDS, transposed + XOR-swizzled
    {
      const float* hsrc = hbuf + (size_t)(tt & 1) * 32768 + (size_t)d * 16384;
#pragma unroll
      for (int i = 0; i < 8; i++) {
        int f = tid + i * 512;          // float4 index 0..4095
        int bb = f >> 6;
        int k4 = (f & 63) * 4;
        float4 v = *(const float4*)&hsrc[(size_t)f * 4];
        int col = bb ^ ((k4 >> 2) & 63);
        h_s[(k4 + 0) * 64 + col] = v.x;
        h_s[(k4 + 1) * 64 + col] = v.y;
        h_s[(k4 + 2) * 64 + col] = v.z;
        h_s[(k4 + 3) * 64 + col] = v.w;
      }
    }
    __syncthreads();
    // GEMV: rows 0..7, k in [ks*32, ks*32+32); h reused across 8 rows from registers
    float pr[8];
#pragma unroll
    for (int r = 0; r < 8; r++) pr[r] = 0.f;
    int kb = ks * 32;
#pragma unroll
    for (int kk = 0; kk < 32; kk += 4) {
      int k = kb + kk;
      int col = b ^ ((k >> 2) & 63);
      float h0 = h_s[(k + 0) * 64 + col];
      float h1 = h_s[(k + 1) * 64 + col];
      float h2 = h_s[(k + 2) * 64 + col];
      float h3 = h_s[(k + 3) * 64 + col];
#pragma unroll
      for (int r = 0; r < 8; r++) {
        float4 wv = *(const float4*)&w_s[r][k];
        pr[r] += wv.x * h0 + wv.y * h1 + wv.z * h2 + wv.w * h3;
      }
    }
#pragma unroll
    for (int r = 0; r < 8; r++) g_p[(ks * 8 + r) * 64 + b] = pr[r];
    __syncthreads();
    // pointwise + state update (threads ks<2; uo = ks)
    if (ks < 2) {
      int u = ug * 2 + ks;
      float gv[4] = {gin0, gin1, gin2, gin3};
#pragma unroll
      for (int g = 0; g < 4; g++) {
        int row = g * 2 + ks;
        float s = gv[g];
#pragma unroll
        for (int q = 0; q < 8; q++) s += g_p[(q * 8 + row) * 64 + b];
        gv[g] = s;
      }
      c = sigmoidf_(gv[1]) * c + sigmoidf_(gv[0]) * tanhf(gv[2]);
      float h = sigmoidf_(gv[3]) * tanhf(c);
      hbuf[(size_t)((tt + 1) & 1) * 32768 + (size_t)d * 16384 + (size_t)b * 256 + u] = h;
      seq_out[((size_t)t * 64 + b) * 512 + d * 256 + u] = h;
    }
    if (tt < 255) BAR();
  }
}

// ---------------- emissions: em[tb][tag] = seq[tb]·out_w[tag] + out_b[tag] ----------------
__global__ void k_emis(const float* __restrict__ seq, const float* __restrict__ out_w,
                       const float* __restrict__ out_b, float* __restrict__ em) {
  __shared__ float ow[TAGS * 512];
  int tid = threadIdx.x;
  for (int i = tid; i < TAGS * 512; i += 256) ow[i] = out_w[i];
  __syncthreads();
  int lane = tid & 63;
  int row = blockIdx.x * 4 + (tid >> 6);
  const float* s = seq + (size_t)row * 512;
  float p[TAGS];
#pragma unroll
  for (int t = 0; t < TAGS; t++) p[t] = 0.f;
#pragma unroll
  for (int kk = 0; kk < 8; kk++) {
    float sv = s[lane + kk * 64];
#pragma unroll
    for (int t = 0; t < TAGS; t++) p[t] += sv * ow[t * 512 + lane + kk * 64];
  }
#pragma unroll
  for (int t = 0; t < TAGS; t++) {
    float v = p[t];
#pragma unroll
    for (int off = 32; off > 0; off >>= 1) v += __shfl_down(v, off, 64);
    if (lane == 0) em[(size_t)row * TAGS + t] = v + out_b[t];
  }
}

// ---------------- Viterbi: one wave per batch ----------------
__global__ void k_viterbi(const float* __restrict__ em, const float* __restrict__ start_t,
                          const float* __restrict__ end_t, const float* __restrict__ trans,
                          float* __restrict__ out) {
  int b = blockIdx.x;
  int lane = threadIdx.x;   // 64 threads, lanes 0..8 active for tags
  __shared__ unsigned char hist[255 * TAGS];
  float tin[TAGS];
#pragma unroll
  for (int p = 0; p < TAGS; p++) tin[p] = (lane < TAGS) ? trans[p * TAGS + lane] : 0.f;
  float score = -1e30f;
  if (lane < TAGS) score = start_t[lane] + em[(size_t)b * TAGS + lane];
  for (int t = 1; t < 256; t++) {
    float best = -1e30f; int bp = 0;
#pragma unroll
    for (int p = 0; p < TAGS; p++) {
      float v = __shfl(score, p, 64) + tin[p];
      if (v > best) { best = v; bp = p; }   // strict > + ascending p == first-max (jnp.argmax)
    }
    if (lane < TAGS) {
      score = best + em[(size_t)(t * 64 + b) * TAGS + lane];
      hist[(t - 1) * TAGS + lane] = (unsigned char)bp;
    }
  }
  float fin = (lane < TAGS) ? (score + end_t[lane]) : -1e30f;
  float bsc = -1e30f; int bl = 0;
#pragma unroll
  for (int p = 0; p < TAGS; p++) {
    float v = __shfl(fin, p, 64);
    if (v > bsc) { bsc = v; bl = p; }
  }
  __syncthreads();
  if (lane == 0) {
    out[(size_t)16384 + b] = bsc;          // best_score[b]
    int tag = bl;
    out[(size_t)b * 256 + 255] = (float)tag;
    for (int t = 254; t >= 0; t--) {
      tag = hist[t * TAGS + tag];
      out[(size_t)b * 256 + t] = (float)tag;
    }
  }
}

extern "C" void kernel_launch(void* const* d_in, const int* in_sizes, int n_in,
                              void* d_out, int out_size, void* d_ws, size_t ws_size,
                              hipStream_t stream) {
  const int*   x       = (const int*)d_in[0];
  const float* table   = (const float*)d_in[1];
  const float* w_ih    = (const float*)d_in[2];   // [2][2][1024][512]
  const float* w_hh    = (const float*)d_in[3];   // [2][2][1024][256]
  const float* b_ih    = (const float*)d_in[4];   // [2][2][1024]
  const float* b_hh    = (const float*)d_in[5];
  const float* out_w   = (const float*)d_in[6];   // [9][512]
  const float* out_b   = (const float*)d_in[7];
  const float* start_t = (const float*)d_in[8];
  const float* end_t   = (const float*)d_in[9];
  const float* trans   = (const float*)d_in[10];  // [9][9]
  float* out = (float*)d_out;
  float* ws = (float*)d_ws;

  float* seq0   = ws;                     // 16384*512  = 8,388,608
  float* seq1   = seq0 + 8388608;         // 8,388,608
  float* gatesT = seq1 + 8388608;         // 256*2048*64 = 33,554,432
  float* em     = gatesT + 33554432;      // 147,456
  float* hbuf   = em + 147456;            // 2*2*64*256 = 65,536
  int*   barp   = (int*)(hbuf + 65536);   // 2 ints
  // total ~202 MB

  hipMemsetAsync(barp, 0, 2 * sizeof(int), stream);
  k_gather<<<8192, 256, 0, stream>>>(x, table, seq0);

  dim3 gg(128, 16);
  // layer 0
  k_gemm_gates<<<gg, 256, 0, stream>>>(w_ih, seq0, b_ih, b_hh, gatesT);
  k_lstm_rec<<<NWG, 512, 0, stream>>>(gatesT, w_hh, seq1, hbuf, barp, 0);
  // layer 1
  k_gemm_gates<<<gg, 256, 0, stream>>>(w_ih + 1048576, seq1, b_ih + 2048, b_hh + 2048, gatesT);
  k_lstm_rec<<<NWG, 512, 0, stream>>>(gatesT, w_hh + 524288, seq0, hbuf, barp, 256);
  // emissions + viterbi
  k_emis<<<4096, 256, 0, stream>>>(seq0, out_w, out_b, em);
  k_viterbi<<<64, 64, 0, stream>>>(em, start_t, end_t, trans, out);
}

// Round 3
// 5366.156 us; speedup vs baseline: 2.2867x; 2.2867x over previous
//
#include <hip/hip_runtime.h>
#include <math.h>

#define TAGS 9

static __device__ __forceinline__ float sigmoidf_(float x) {
  return 1.0f / (1.0f + expf(-x));
}

// MALL-coherent (cross-XCD) plain data movement: same cache-bypass bits the
// compiler emits for agent-scope atomics, but at dwordx4 width.
__device__ __forceinline__ float4 ld4_sc(const float* p) {
  float4 r;
  asm volatile("global_load_dwordx4 %0, %1, off sc0 sc1" : "=v"(r) : "v"(p) : "memory");
  return r;
}
__device__ __forceinline__ void st1_sc(float* p, float v) {
  asm volatile("global_store_dword %0, %1, off sc0 sc1" :: "v"(p), "v"(v) : "memory");
}
__device__ __forceinline__ void waitcnt0() {
  asm volatile("s_waitcnt vmcnt(0)" ::: "memory");
}

// ---------------- embedding gather ----------------
__global__ void k_gather(const int* __restrict__ x, const float* __restrict__ table,
                         float* __restrict__ seq) {
  int tid = blockIdx.x * 256 + threadIdx.x;
  int row = tid >> 7;
  int e4 = tid & 127;
  int idx = x[row];
  const float4* src = (const float4*)(table + (size_t)idx * 512);
  float4* dst = (float4*)(seq + (size_t)row * 512);
  dst[e4] = src[e4];
}

// ---------------- gates GEMM, transposed output ----------------
// gatesT[t][m][b] = sum_k A[m][k] * B[t*64+b][k] + bias1[m] + bias2[m]
__global__ __launch_bounds__(256, 2)
void k_gemm_gates(const float* __restrict__ A, const float* __restrict__ B,
                  const float* __restrict__ bias1, const float* __restrict__ bias2,
                  float* __restrict__ gatesT) {
  __shared__ float As[16][132];
  __shared__ float Bs[16][132];
  int tid = threadIdx.x;
  int tx = tid & 15, ty = tid >> 4;
  int n0 = blockIdx.x * 128, m0 = blockIdx.y * 128;
  int lr = tid >> 2;
  int lk = (tid & 3) * 4;
  float acc[8][8];
#pragma unroll
  for (int i = 0; i < 8; i++)
#pragma unroll
    for (int j = 0; j < 8; j++) acc[i][j] = 0.f;
  const float* Ab = A + (size_t)m0 * 512;
  const float* Bb = B + (size_t)n0 * 512;
  for (int k0 = 0; k0 < 512; k0 += 16) {
    float4 a0 = *(const float4*)&Ab[(size_t)lr * 512 + k0 + lk];
    float4 a1 = *(const float4*)&Ab[(size_t)(lr + 64) * 512 + k0 + lk];
    float4 w0 = *(const float4*)&Bb[(size_t)lr * 512 + k0 + lk];
    float4 w1 = *(const float4*)&Bb[(size_t)(lr + 64) * 512 + k0 + lk];
    __syncthreads();
    As[lk + 0][lr] = a0.x; As[lk + 1][lr] = a0.y; As[lk + 2][lr] = a0.z; As[lk + 3][lr] = a0.w;
    As[lk + 0][lr + 64] = a1.x; As[lk + 1][lr + 64] = a1.y; As[lk + 2][lr + 64] = a1.z; As[lk + 3][lr + 64] = a1.w;
    Bs[lk + 0][lr] = w0.x; Bs[lk + 1][lr] = w0.y; Bs[lk + 2][lr] = w0.z; Bs[lk + 3][lr] = w0.w;
    Bs[lk + 0][lr + 64] = w1.x; Bs[lk + 1][lr + 64] = w1.y; Bs[lk + 2][lr + 64] = w1.z; Bs[lk + 3][lr + 64] = w1.w;
    __syncthreads();
#pragma unroll
    for (int kk = 0; kk < 16; kk++) {
      float4 av0 = *(const float4*)&As[kk][ty * 4];
      float4 av1 = *(const float4*)&As[kk][ty * 4 + 64];
      float4 bv0 = *(const float4*)&Bs[kk][tx * 4];
      float4 bv1 = *(const float4*)&Bs[kk][tx * 4 + 64];
      float am[8] = {av0.x, av0.y, av0.z, av0.w, av1.x, av1.y, av1.z, av1.w};
      float bn[8] = {bv0.x, bv0.y, bv0.z, bv0.w, bv1.x, bv1.y, bv1.z, bv1.w};
#pragma unroll
      for (int i = 0; i < 8; i++)
#pragma unroll
        for (int j = 0; j < 8; j++) acc[i][j] += am[i] * bn[j];
    }
  }
  int t0 = n0 >> 6;
#pragma unroll
  for (int i = 0; i < 8; i++) {
    int m = m0 + ((i < 4) ? (ty * 4 + i) : (64 + ty * 4 + (i - 4)));
    float bs = bias1[m] + bias2[m];
    float4 o0 = {acc[i][0] + bs, acc[i][1] + bs, acc[i][2] + bs, acc[i][3] + bs};
    float4 o1 = {acc[i][4] + bs, acc[i][5] + bs, acc[i][6] + bs, acc[i][7] + bs};
    *(float4*)&gatesT[((size_t)t0 * 2048 + m) * 64 + tx * 4] = o0;
    *(float4*)&gatesT[((size_t)(t0 + 1) * 2048 + m) * 64 + tx * 4] = o1;
  }
}

// ---------------- distributed-weight LSTM layer, MALL-exchange, fence-free ----------------
// 128 WGs x 512 thr (1/CU). WG = (dir d, 4 units u0..u0+3) -> 16 gate rows LDS-resident.
// Per step: h (64KB/dir) sc-loaded coalesced -> LDS; 8-way k-split GEMV (h reused across
// 16 rows from regs); partials combined; pointwise by 256 threads; h published via sc-stores;
// sync via relaxed agent split-counters per (dir, step). No fences anywhere.
__global__ __launch_bounds__(512, 1)
void k_lstm_rec(const float* __restrict__ gatesT,   // [256][2048][64]
                const float* __restrict__ whh,      // [2][1024][256] layer slice
                float* __restrict__ seq_out,        // [16384][512]
                float* __restrict__ hbuf,           // [2 slots][2 dir][64][256]
                int* __restrict__ arr) {            // [2 dir][256][4]
  __shared__ float h_s[64 * 257];     // [b][k] pitch 257: GEMV reads 2-way (free)
  __shared__ float w_s[16][256];      // local row r = gate*4 + uo
  __shared__ float p_s[8][16][64];    // [kq][r][b]
  int wg = blockIdx.x, tid = threadIdx.x;
  int d = wg >> 6;                    // 64 WGs per direction
  int u0 = (wg & 63) * 4;
  int b = tid & 63, kq = tid >> 6;    // kq 0..7: 32-wide k slice
  for (int i = tid; i < 4096; i += 512) {
    int r = i >> 8, k = i & 255;
    int g = r >> 2, uo = r & 3;
    w_s[r][k] = whh[((size_t)d * 1024 + g * 256 + u0 + uo) * 256 + k];
  }
  __syncthreads();
  int uo = tid >> 6;                  // pointwise role for tid<256
  float c = 0.f;

  for (int tt = 0; tt < 256; ++tt) {
    int t = d ? 255 - tt : tt;
    // prefetch input-gate contributions (cached loads; overlap with h staging)
    float gin0 = 0.f, gin1 = 0.f, gin2 = 0.f, gin3 = 0.f;
    if (tid < 256) {
      const float* gp = gatesT + ((size_t)t * 2048 + d * 1024 + u0 + uo) * 64 + b;
      gin0 = gp[0 * 16384];
      gin1 = gp[1 * 16384];
      gin2 = gp[2 * 16384];
      gin3 = gp[3 * 16384];
    }
    // stage h: coalesced MALL loads -> LDS
    const float* hcur = hbuf + (size_t)(tt & 1) * 32768 + (size_t)d * 16384;
    float4 hv[8];
#pragma unroll
    for (int i = 0; i < 8; i++) hv[i] = ld4_sc(hcur + (size_t)(tid + i * 512) * 4);
    waitcnt0();
#pragma unroll
    for (int i = 0; i < 8; i++) {
      int f = tid + i * 512;
      float* hp = &h_s[(f >> 6) * 257 + (f & 63) * 4];
      hp[0] = hv[i].x; hp[1] = hv[i].y; hp[2] = hv[i].z; hp[3] = hv[i].w;
    }
    __syncthreads();
    // GEMV: 16 rows x own 32-k slice for batch b
    float pr[16];
#pragma unroll
    for (int r = 0; r < 16; r++) pr[r] = 0.f;
    const int hb = b * 257 + kq * 32;
#pragma unroll
    for (int j = 0; j < 8; j++) {
      float h0 = h_s[hb + j * 4 + 0], h1 = h_s[hb + j * 4 + 1];
      float h2 = h_s[hb + j * 4 + 2], h3 = h_s[hb + j * 4 + 3];
#pragma unroll
      for (int r = 0; r < 16; r++) {
        float4 w = *(const float4*)&w_s[r][kq * 32 + j * 4];
        pr[r] += w.x * h0 + w.y * h1 + w.z * h2 + w.w * h3;
      }
    }
#pragma unroll
    for (int r = 0; r < 16; r++) p_s[kq][r][b] = pr[r];
    __syncthreads();
    // combine + pointwise + publish
    if (tid < 256) {
      float gv[4] = {gin0, gin1, gin2, gin3};
#pragma unroll
      for (int g = 0; g < 4; g++) {
        int r = g * 4 + uo;
        float s = gv[g];
#pragma unroll
        for (int q = 0; q < 8; q++) s += p_s[q][r][b];
        gv[g] = s;
      }
      c = sigmoidf_(gv[1]) * c + sigmoidf_(gv[0]) * tanhf(gv[2]);
      float h = sigmoidf_(gv[3]) * tanhf(c);
      float* hnext = hbuf + (size_t)((tt + 1) & 1) * 32768 + (size_t)d * 16384;
      st1_sc(hnext + b * 256 + u0 + uo, h);
      seq_out[((size_t)t * 64 + b) * 512 + d * 256 + u0 + uo] = h;
    }
    if (tt < 255) {
      waitcnt0();            // each thread drains its own h-stores
      __syncthreads();       // all stores of this WG are at MALL
      if (tid == 0) {
        int* ap = arr + ((size_t)d * 256 + tt) * 4;
        __hip_atomic_fetch_add(&ap[wg & 3], 1, __ATOMIC_RELAXED, __HIP_MEMORY_SCOPE_AGENT);
        while (true) {
          int s = __hip_atomic_load(&ap[0], __ATOMIC_RELAXED, __HIP_MEMORY_SCOPE_AGENT)
                + __hip_atomic_load(&ap[1], __ATOMIC_RELAXED, __HIP_MEMORY_SCOPE_AGENT)
                + __hip_atomic_load(&ap[2], __ATOMIC_RELAXED, __HIP_MEMORY_SCOPE_AGENT)
                + __hip_atomic_load(&ap[3], __ATOMIC_RELAXED, __HIP_MEMORY_SCOPE_AGENT);
          if (s >= 64) break;
          __builtin_amdgcn_s_sleep(1);
        }
      }
      __syncthreads();
    }
  }
}

// ---------------- emissions ----------------
__global__ void k_emis(const float* __restrict__ seq, const float* __restrict__ out_w,
                       const float* __restrict__ out_b, float* __restrict__ em) {
  __shared__ float ow[TAGS * 512];
  int tid = threadIdx.x;
  for (int i = tid; i < TAGS * 512; i += 256) ow[i] = out_w[i];
  __syncthreads();
  int lane = tid & 63;
  int row = blockIdx.x * 4 + (tid >> 6);
  const float* s = seq + (size_t)row * 512;
  float p[TAGS];
#pragma unroll
  for (int t = 0; t < TAGS; t++) p[t] = 0.f;
#pragma unroll
  for (int kk = 0; kk < 8; kk++) {
    float sv = s[lane + kk * 64];
#pragma unroll
    for (int t = 0; t < TAGS; t++) p[t] += sv * ow[t * 512 + lane + kk * 64];
  }
#pragma unroll
  for (int t = 0; t < TAGS; t++) {
    float v = p[t];
#pragma unroll
    for (int off = 32; off > 0; off >>= 1) v += __shfl_down(v, off, 64);
    if (lane == 0) em[(size_t)row * TAGS + t] = v + out_b[t];
  }
}

// ---------------- Viterbi ----------------
__global__ void k_viterbi(const float* __restrict__ em, const float* __restrict__ start_t,
                          const float* __restrict__ end_t, const float* __restrict__ trans,
                          float* __restrict__ out) {
  int b = blockIdx.x;
  int lane = threadIdx.x;
  __shared__ unsigned char hist[255 * TAGS];
  float tin[TAGS];
#pragma unroll
  for (int p = 0; p < TAGS; p++) tin[p] = (lane < TAGS) ? trans[p * TAGS + lane] : 0.f;
  float score = -1e30f;
  if (lane < TAGS) score = start_t[lane] + em[(size_t)b * TAGS + lane];
  for (int t = 1; t < 256; t++) {
    float best = -1e30f; int bp = 0;
#pragma unroll
    for (int p = 0; p < TAGS; p++) {
      float v = __shfl(score, p, 64) + tin[p];
      if (v > best) { best = v; bp = p; }
    }
    if (lane < TAGS) {
      score = best + em[(size_t)(t * 64 + b) * TAGS + lane];
      hist[(t - 1) * TAGS + lane] = (unsigned char)bp;
    }
  }
  float fin = (lane < TAGS) ? (score + end_t[lane]) : -1e30f;
  float bsc = -1e30f; int bl = 0;
#pragma unroll
  for (int p = 0; p < TAGS; p++) {
    float v = __shfl(fin, p, 64);
    if (v > bsc) { bsc = v; bl = p; }
  }
  __syncthreads();
  if (lane == 0) {
    out[(size_t)16384 + b] = bsc;
    int tag = bl;
    out[(size_t)b * 256 + 255] = (float)tag;
    for (int t = 254; t >= 0; t--) {
      tag = hist[t * TAGS + tag];
      out[(size_t)b * 256 + t] = (float)tag;
    }
  }
}

extern "C" void kernel_launch(void* const* d_in, const int* in_sizes, int n_in,
                              void* d_out, int out_size, void* d_ws, size_t ws_size,
                              hipStream_t stream) {
  const int*   x       = (const int*)d_in[0];
  const float* table   = (const float*)d_in[1];
  const float* w_ih    = (const float*)d_in[2];   // [2][2][1024][512]
  const float* w_hh    = (const float*)d_in[3];   // [2][2][1024][256]
  const float* b_ih    = (const float*)d_in[4];
  const float* b_hh    = (const float*)d_in[5];
  const float* out_w   = (const float*)d_in[6];
  const float* out_b   = (const float*)d_in[7];
  const float* start_t = (const float*)d_in[8];
  const float* end_t   = (const float*)d_in[9];
  const float* trans   = (const float*)d_in[10];
  float* out = (float*)d_out;
  float* ws = (float*)d_ws;

  float* seq0   = ws;                       // 8,388,608
  float* seq1   = seq0 + 8388608;           // 8,388,608
  float* gatesT = seq1 + 8388608;           // 33,554,432
  float* em     = gatesT + 33554432;        // 147,456
  float* hbufA  = em + 147456;              // 65,536 (2 slots x 2 dir x 64 x 256)
  float* hbufB  = hbufA + 65536;            // 65,536
  int*   arrA   = (int*)(hbufB + 65536);    // 2,048 ints
  int*   arrB   = arrA + 2048;              // 2,048 ints
  // total ~203 MB

  hipMemsetAsync(arrA, 0, 4096 * sizeof(int), stream);
  hipMemsetAsync(hbufA, 0, 32768 * sizeof(float), stream);   // slot 0 zeros
  hipMemsetAsync(hbufB, 0, 32768 * sizeof(float), stream);

  k_gather<<<8192, 256, 0, stream>>>(x, table, seq0);

  dim3 gg(128, 16);
  k_gemm_gates<<<gg, 256, 0, stream>>>(w_ih, seq0, b_ih, b_hh, gatesT);
  k_lstm_rec<<<128, 512, 0, stream>>>(gatesT, w_hh, seq1, hbufA, arrA);
  k_gemm_gates<<<gg, 256, 0, stream>>>(w_ih + 1048576, seq1, b_ih + 2048, b_hh + 2048, gatesT);
  k_lstm_rec<<<128, 512, 0, stream>>>(gatesT, w_hh + 524288, seq0, hbufB, arrB);
  k_emis<<<4096, 256, 0, stream>>>(seq0, out_w, out_b, em);
  k_viterbi<<<64, 64, 0, stream>>>(em, start_t, end_t, trans, out);
}

// Round 4
// 4961.339 us; speedup vs baseline: 2.4733x; 1.0816x over previous
//
#include <hip/hip_runtime.h>
#include <math.h>

#define TAGS 9

static __device__ __forceinline__ float sigmoidf_(float x) {
  return 1.0f / (1.0f + expf(-x));
}

// MALL-coherent (cross-XCD) plain data movement (validated rounds 2-3).
__device__ __forceinline__ float ld1_sc(const float* p) {
  float r;
  asm volatile("global_load_dword %0, %1, off sc0 sc1" : "=v"(r) : "v"(p) : "memory");
  return r;
}
__device__ __forceinline__ void st1_sc(float* p, float v) {
  asm volatile("global_store_dword %0, %1, off sc0 sc1" :: "v"(p), "v"(v) : "memory");
}
__device__ __forceinline__ void waitcnt0() {
  asm volatile("s_waitcnt vmcnt(0)" ::: "memory");
}

// ---------------- pack Whh into per-WG scalar-streamable layout ----------------
// wPack[L][wg][k][rr]: wg = d*64+ug (4 units), rr = gate*4 + uo. 2*128*256*16 floats.
__global__ void k_pack_w(const float* __restrict__ whh, float* __restrict__ wPack) {
  int i = blockIdx.x * 256 + threadIdx.x;       // < 1048576
  int rr = i & 15;
  int k = (i >> 4) & 255;
  int wg = (i >> 12) & 127;
  int L = i >> 19;
  int d = wg >> 6, ug = wg & 63;
  int row = d * 1024 + (rr >> 2) * 256 + ug * 4 + (rr & 3);
  wPack[i] = whh[(size_t)L * 524288 + (size_t)row * 256 + k];
}

// owT[ch][12]: transposed out_w (padded stride 12 for aligned x4/x4/x1 scalar loads)
__global__ void k_pack_ow(const float* __restrict__ out_w, float* __restrict__ owT) {
  int i = blockIdx.x * 256 + threadIdx.x;       // < 4608
  int tag = i % 9, ch = i / 9;
  owT[ch * 12 + tag] = out_w[tag * 512 + ch];
}

// ---------------- fused gather + transpose: seqT[ch][tb] = table[x[tb]][ch] ----------------
__global__ __launch_bounds__(256, 1)
void k_gatherT(const int* __restrict__ x, const float* __restrict__ table,
               float* __restrict__ seqT) {
  __shared__ float tile[64 * 513];
  __shared__ int x_s[64];
  int wg = blockIdx.x;           // 256 WGs x 64 tb
  int tid = threadIdx.x;
  int tb0 = wg * 64;
  if (tid < 64) x_s[tid] = x[tb0 + tid];
  __syncthreads();
#pragma unroll
  for (int i = 0; i < 32; i++) {
    int idx = tid + i * 256;     // float4 index over [64 rows][128 f4]
    int r = idx >> 7, c4 = (idx & 127) * 4;
    float4 v = *(const float4*)&table[(size_t)x_s[r] * 512 + c4];
    float* tp = &tile[r * 513 + c4];
    tp[0] = v.x; tp[1] = v.y; tp[2] = v.z; tp[3] = v.w;
  }
  __syncthreads();
#pragma unroll
  for (int i = 0; i < 128; i++) {
    int j = tid + i * 256;       // over [512 ch][64 b]
    int ch = j >> 6, b = j & 63;
    seqT[(size_t)ch * 16384 + tb0 + b] = tile[b * 513 + ch];
  }
}

// ---------------- gates GEMM: gatesT[t][m][b] = sum_k A[m][k]*seqT[k][t*64+b] + biases ----------------
__global__ __launch_bounds__(256, 2)
void k_gemm_gates(const float* __restrict__ A, const float* __restrict__ seqT,
                  const float* __restrict__ bias1, const float* __restrict__ bias2,
                  float* __restrict__ gatesT) {
  __shared__ float As[16][132];
  __shared__ float Bs[16][132];
  int tid = threadIdx.x;
  int tx = tid & 15, ty = tid >> 4;
  int n0 = blockIdx.x * 128, m0 = blockIdx.y * 128;
  int lr = tid >> 2;
  int lk = (tid & 3) * 4;
  int bkk = tid >> 4, bn8 = (tid & 15) * 8;
  float acc[8][8];
#pragma unroll
  for (int i = 0; i < 8; i++)
#pragma unroll
    for (int j = 0; j < 8; j++) acc[i][j] = 0.f;
  const float* Ab = A + (size_t)m0 * 512;
  for (int k0 = 0; k0 < 512; k0 += 16) {
    float4 a0 = *(const float4*)&Ab[(size_t)lr * 512 + k0 + lk];
    float4 a1 = *(const float4*)&Ab[(size_t)(lr + 64) * 512 + k0 + lk];
    const float* Bp = seqT + (size_t)(k0 + bkk) * 16384 + n0 + bn8;
    float4 b0 = *(const float4*)Bp;
    float4 b1 = *(const float4*)(Bp + 4);
    __syncthreads();
    As[lk + 0][lr] = a0.x; As[lk + 1][lr] = a0.y; As[lk + 2][lr] = a0.z; As[lk + 3][lr] = a0.w;
    As[lk + 0][lr + 64] = a1.x; As[lk + 1][lr + 64] = a1.y; As[lk + 2][lr + 64] = a1.z; As[lk + 3][lr + 64] = a1.w;
    *(float4*)&Bs[bkk][bn8] = b0;
    *(float4*)&Bs[bkk][bn8 + 4] = b1;
    __syncthreads();
#pragma unroll
    for (int kk = 0; kk < 16; kk++) {
      float4 av0 = *(const float4*)&As[kk][ty * 4];
      float4 av1 = *(const float4*)&As[kk][ty * 4 + 64];
      float4 bv0 = *(const float4*)&Bs[kk][tx * 4];
      float4 bv1 = *(const float4*)&Bs[kk][tx * 4 + 64];
      float am[8] = {av0.x, av0.y, av0.z, av0.w, av1.x, av1.y, av1.z, av1.w};
      float bn[8] = {bv0.x, bv0.y, bv0.z, bv0.w, bv1.x, bv1.y, bv1.z, bv1.w};
#pragma unroll
      for (int i = 0; i < 8; i++)
#pragma unroll
        for (int j = 0; j < 8; j++) acc[i][j] += am[i] * bn[j];
    }
  }
  int t0 = n0 >> 6;
#pragma unroll
  for (int i = 0; i < 8; i++) {
    int m = m0 + ((i < 4) ? (ty * 4 + i) : (64 + ty * 4 + (i - 4)));
    float bs = bias1[m] + bias2[m];
    float4 o0 = {acc[i][0] + bs, acc[i][1] + bs, acc[i][2] + bs, acc[i][3] + bs};
    float4 o1 = {acc[i][4] + bs, acc[i][5] + bs, acc[i][6] + bs, acc[i][7] + bs};
    *(float4*)&gatesT[((size_t)t0 * 2048 + m) * 64 + tx * 4] = o0;
    *(float4*)&gatesT[((size_t)(t0 + 1) * 2048 + m) * 64 + tx * 4] = o1;
  }
}

// ---------------- LSTM recurrence: scalar-pipe weights, register h, MALL exchange ----------------
// 128 WGs x 512 thr. WG=(d, 4 units). Thread=(b=tid&63, kq=wave 0..7 of 32-k slice).
// Weights stream via s_load from wPack (wave-uniform). h sc-loaded direct to regs.
// LDS only holds the 32KB partials buffer.
__global__ __launch_bounds__(512, 1)
void k_lstm_rec(const float* __restrict__ gatesT,   // [256][2048][64]
                const float* __restrict__ wPack,    // [128][256][16] this layer
                const float* __restrict__ whh_unused,
                float* __restrict__ seqT_out,       // [512][16384]
                float* __restrict__ hbuf,           // [2 slots][2 dir][256 u][64 b]
                int* __restrict__ arr) {            // [2 dir][256]
  __shared__ float p_s[8 * 16 * 64];
  int wg = blockIdx.x, tid = threadIdx.x;
  int d = wg >> 6;
  int u0 = (wg & 63) * 4;
  int b = tid & 63;
  int kq = __builtin_amdgcn_readfirstlane(tid >> 6);   // wave index 0..7
  int uo = tid >> 6;                                   // pointwise role (tid<256)
  const float4* wp4 = (const float4*)(wPack + ((size_t)wg * 256 + kq * 32) * 16);
  float c = 0.f;

  for (int tt = 0; tt < 256; ++tt) {
    int t = d ? 255 - tt : tt;
    // prefetch this step's input-gate values (normal cached loads)
    float gin0 = 0.f, gin1 = 0.f, gin2 = 0.f, gin3 = 0.f;
    if (tid < 256) {
      const float* gp = gatesT + ((size_t)t * 2048 + d * 1024 + u0 + uo) * 64 + b;
      gin0 = gp[0 * 16384];
      gin1 = gp[1 * 16384];
      gin2 = gp[2 * 16384];
      gin3 = gp[3 * 16384];
    }
    // h slice for this wave: 32 coalesced MALL loads direct to registers
    const float* hcur = hbuf + (size_t)(tt & 1) * 32768 + (size_t)d * 16384 + kq * 32 * 64 + b;
    float hreg[32];
#pragma unroll
    for (int j = 0; j < 32; j++) hreg[j] = ld1_sc(hcur + j * 64);
    waitcnt0();
    // GEMV: acc[rr] += wPack[k][rr] * h[k]; w chunks are wave-uniform (scalar pipe)
    float acc[16];
#pragma unroll
    for (int r = 0; r < 16; r++) acc[r] = 0.f;
#pragma unroll 8
    for (int j = 0; j < 32; j++) {
      float hj = hreg[j];
      float4 w0 = wp4[j * 4 + 0];
      float4 w1 = wp4[j * 4 + 1];
      float4 w2 = wp4[j * 4 + 2];
      float4 w3 = wp4[j * 4 + 3];
      acc[0] += w0.x * hj;  acc[1] += w0.y * hj;  acc[2] += w0.z * hj;  acc[3] += w0.w * hj;
      acc[4] += w1.x * hj;  acc[5] += w1.y * hj;  acc[6] += w1.z * hj;  acc[7] += w1.w * hj;
      acc[8] += w2.x * hj;  acc[9] += w2.y * hj;  acc[10] += w2.z * hj; acc[11] += w2.w * hj;
      acc[12] += w3.x * hj; acc[13] += w3.y * hj; acc[14] += w3.z * hj; acc[15] += w3.w * hj;
    }
#pragma unroll
    for (int r = 0; r < 16; r++) p_s[(kq * 16 + r) * 64 + b] = acc[r];
    __syncthreads();
    // combine + pointwise + publish (tid<256; unit u0+uo, batch b)
    if (tid < 256) {
      float gv[4] = {gin0, gin1, gin2, gin3};
#pragma unroll
      for (int g = 0; g < 4; g++) {
        int rr = g * 4 + uo;
        float s = gv[g];
#pragma unroll
        for (int q = 0; q < 8; q++) s += p_s[(q * 16 + rr) * 64 + b];
        gv[g] = s;
      }
      c = sigmoidf_(gv[1]) * c + sigmoidf_(gv[0]) * tanhf(gv[2]);
      float h = sigmoidf_(gv[3]) * tanhf(c);
      float* hnext = hbuf + (size_t)((tt + 1) & 1) * 32768 + (size_t)d * 16384;
      st1_sc(hnext + (u0 + uo) * 64 + b, h);                          // coalesced 256B/wave
      seqT_out[(size_t)(d * 256 + u0 + uo) * 16384 + t * 64 + b] = h; // coalesced 256B/wave
    }
    if (tt < 255) {
      waitcnt0();            // drain own h-stores (at MALL when vmcnt==0)
      __syncthreads();
      if (tid == 0) {
        int* ap = arr + d * 256 + tt;
        __hip_atomic_fetch_add(ap, 1, __ATOMIC_RELAXED, __HIP_MEMORY_SCOPE_AGENT);
        while (__hip_atomic_load(ap, __ATOMIC_RELAXED, __HIP_MEMORY_SCOPE_AGENT) < 64)
          __builtin_amdgcn_s_sleep(2);
      }
      __syncthreads();
    }
  }
}

// ---------------- emissions: em[tb][tag] = sum_ch seqT[ch][tb]*owT[ch][tag] + out_b ----------------
__global__ __launch_bounds__(256, 4)
void k_emis(const float* __restrict__ seqT, const float* __restrict__ owT,
            const float* __restrict__ out_b, float* __restrict__ em) {
  int tb = blockIdx.x * 256 + threadIdx.x;   // 64 WGs
  float p[TAGS];
#pragma unroll
  for (int t = 0; t < TAGS; t++) p[t] = 0.f;
  for (int ch = 0; ch < 512; ch++) {
    float sv = seqT[(size_t)ch * 16384 + tb];
    const float4* o4 = (const float4*)(owT + ch * 12);   // wave-uniform -> scalar loads
    float4 oa = o4[0], ob = o4[1];
    float oc = owT[ch * 12 + 8];
    p[0] += sv * oa.x; p[1] += sv * oa.y; p[2] += sv * oa.z; p[3] += sv * oa.w;
    p[4] += sv * ob.x; p[5] += sv * ob.y; p[6] += sv * ob.z; p[7] += sv * ob.w;
    p[8] += sv * oc;
  }
#pragma unroll
  for (int t = 0; t < TAGS; t++) em[(size_t)tb * TAGS + t] = p[t] + out_b[t];
}

// ---------------- Viterbi: one wave per batch ----------------
__global__ void k_viterbi(const float* __restrict__ em, const float* __restrict__ start_t,
                          const float* __restrict__ end_t, const float* __restrict__ trans,
                          float* __restrict__ out) {
  int b = blockIdx.x;
  int lane = threadIdx.x;
  __shared__ unsigned char hist[255 * TAGS];
  float tin[TAGS];
#pragma unroll
  for (int p = 0; p < TAGS; p++) tin[p] = (lane < TAGS) ? trans[p * TAGS + lane] : 0.f;
  float score = -1e30f;
  if (lane < TAGS) score = start_t[lane] + em[(size_t)b * TAGS + lane];
  for (int t = 1; t < 256; t++) {
    float best = -1e30f; int bp = 0;
#pragma unroll
    for (int p = 0; p < TAGS; p++) {
      float v = __shfl(score, p, 64) + tin[p];
      if (v > best) { best = v; bp = p; }   // strict > + ascending p == first-max (jnp.argmax)
    }
    if (lane < TAGS) {
      score = best + em[(size_t)(t * 64 + b) * TAGS + lane];
      hist[(t - 1) * TAGS + lane] = (unsigned char)bp;
    }
  }
  float fin = (lane < TAGS) ? (score + end_t[lane]) : -1e30f;
  float bsc = -1e30f; int bl = 0;
#pragma unroll
  for (int p = 0; p < TAGS; p++) {
    float v = __shfl(fin, p, 64);
    if (v > bsc) { bsc = v; bl = p; }
  }
  __syncthreads();
  if (lane == 0) {
    out[(size_t)16384 + b] = bsc;
    int tag = bl;
    out[(size_t)b * 256 + 255] = (float)tag;
    for (int t = 254; t >= 0; t--) {
      tag = hist[t * TAGS + tag];
      out[(size_t)b * 256 + t] = (float)tag;
    }
  }
}

extern "C" void kernel_launch(void* const* d_in, const int* in_sizes, int n_in,
                              void* d_out, int out_size, void* d_ws, size_t ws_size,
                              hipStream_t stream) {
  const int*   x       = (const int*)d_in[0];
  const float* table   = (const float*)d_in[1];
  const float* w_ih    = (const float*)d_in[2];   // [2][2][1024][512]
  const float* w_hh    = (const float*)d_in[3];   // [2][2][1024][256]
  const float* b_ih    = (const float*)d_in[4];
  const float* b_hh    = (const float*)d_in[5];
  const float* out_w   = (const float*)d_in[6];
  const float* out_b   = (const float*)d_in[7];
  const float* start_t = (const float*)d_in[8];
  const float* end_t   = (const float*)d_in[9];
  const float* trans   = (const float*)d_in[10];
  float* out = (float*)d_out;
  float* ws = (float*)d_ws;

  float* seqT0  = ws;                       // 8,388,608  (embeds -> layer-1 output)
  float* seqT1  = seqT0 + 8388608;          // 8,388,608  (layer-0 output)
  float* gatesT = seqT1 + 8388608;          // 33,554,432
  float* em     = gatesT;                   // overlays gatesT (dead by k_emis time)
  float* hbufA  = gatesT + 33554432;        // 65,536
  float* hbufB  = hbufA + 65536;            // 65,536
  float* wPack  = hbufB + 65536;            // 1,048,576 ([2 layers][128][256][16])
  float* owT    = wPack + 1048576;          // 6,144
  int*   arr    = (int*)(owT + 6144);       // 1,024 ints ([2 layers][2 dir][256])
  // total ~206.2 MB

  hipMemsetAsync(arr, 0, 1024 * sizeof(int), stream);
  hipMemsetAsync(hbufA, 0, 32768 * sizeof(float), stream);   // slot 0 zeros
  hipMemsetAsync(hbufB, 0, 32768 * sizeof(float), stream);

  k_pack_w<<<4096, 256, 0, stream>>>(w_hh, wPack);
  k_pack_ow<<<18, 256, 0, stream>>>(out_w, owT);
  k_gatherT<<<256, 256, 0, stream>>>(x, table, seqT0);

  dim3 gg(128, 16);
  k_gemm_gates<<<gg, 256, 0, stream>>>(w_ih, seqT0, b_ih, b_hh, gatesT);
  k_lstm_rec<<<128, 512, 0, stream>>>(gatesT, wPack, w_hh, seqT1, hbufA, arr);
  k_gemm_gates<<<gg, 256, 0, stream>>>(w_ih + 1048576, seqT1, b_ih + 2048, b_hh + 2048, gatesT);
  k_lstm_rec<<<128, 512, 0, stream>>>(gatesT, wPack + 524288, w_hh, seqT0, hbufB, arr + 512);
  k_emis<<<64, 256, 0, stream>>>(seqT0, owT, out_b, em);
  k_viterbi<<<64, 64, 0, stream>>>(em, start_t, end_t, trans, out);
}

// Round 5
// 4613.475 us; speedup vs baseline: 2.6598x; 1.0754x over previous
//
#include <hip/hip_runtime.h>
#include <math.h>

#define TAGS 9

static __device__ __forceinline__ float sigmoidf_(float x) {
  return 1.0f / (1.0f + expf(-x));
}

// MALL-coherent (cross-XCD) plain data movement (validated rounds 2-4).
__device__ __forceinline__ void st1_sc(float* p, float v) {
  asm volatile("global_store_dword %0, %1, off sc0 sc1" :: "v"(p), "v"(v) : "memory");
}
__device__ __forceinline__ void sti_sc(int* p, int v) {
  asm volatile("global_store_dword %0, %1, off sc0 sc1" :: "v"(p), "v"(v) : "memory");
}
__device__ __forceinline__ int ldi_sc(const int* p) {
  int r;
  asm volatile("global_load_dword %0, %1, off sc0 sc1" : "=v"(r) : "v"(p) : "memory");
  return r;
}
__device__ __forceinline__ void waitcnt0() {
  asm volatile("s_waitcnt vmcnt(0)" ::: "memory");
}

// ---------------- pack Whh into per-WG scalar-streamable layout ----------------
// wPack[L][wg][k][rr]: wg = d*64+ug (4 units), rr = gate*4 + uo. 2*128*256*16 floats.
__global__ void k_pack_w(const float* __restrict__ whh, float* __restrict__ wPack) {
  int i = blockIdx.x * 256 + threadIdx.x;       // < 1048576
  int rr = i & 15;
  int k = (i >> 4) & 255;
  int wg = (i >> 12) & 127;
  int L = i >> 19;
  int d = wg >> 6, ug = wg & 63;
  int row = d * 1024 + (rr >> 2) * 256 + ug * 4 + (rr & 3);
  wPack[i] = whh[(size_t)L * 524288 + (size_t)row * 256 + k];
}

// owT[ch][12]: transposed out_w (padded stride 12 for aligned x4/x4/x1 scalar loads)
__global__ void k_pack_ow(const float* __restrict__ out_w, float* __restrict__ owT) {
  int i = blockIdx.x * 256 + threadIdx.x;       // < 4608
  int tag = i % 9, ch = i / 9;
  owT[ch * 12 + tag] = out_w[tag * 512 + ch];
}

// ---------------- fused gather + transpose: seqT[ch][tb] = table[x[tb]][ch] ----------------
__global__ __launch_bounds__(256, 1)
void k_gatherT(const int* __restrict__ x, const float* __restrict__ table,
               float* __restrict__ seqT) {
  __shared__ float tile[64 * 513];
  __shared__ int x_s[64];
  int wg = blockIdx.x;           // 256 WGs x 64 tb
  int tid = threadIdx.x;
  int tb0 = wg * 64;
  if (tid < 64) x_s[tid] = x[tb0 + tid];
  __syncthreads();
#pragma unroll
  for (int i = 0; i < 32; i++) {
    int idx = tid + i * 256;     // float4 index over [64 rows][128 f4]
    int r = idx >> 7, c4 = (idx & 127) * 4;
    float4 v = *(const float4*)&table[(size_t)x_s[r] * 512 + c4];
    float* tp = &tile[r * 513 + c4];
    tp[0] = v.x; tp[1] = v.y; tp[2] = v.z; tp[3] = v.w;
  }
  __syncthreads();
#pragma unroll
  for (int i = 0; i < 128; i++) {
    int j = tid + i * 256;       // over [512 ch][64 b]
    int ch = j >> 6, b = j & 63;
    seqT[(size_t)ch * 16384 + tb0 + b] = tile[b * 513 + ch];
  }
}

// ---------------- gates GEMM: gatesT[t][m][b] = sum_k A[m][k]*seqT[k][t*64+b] + biases ----------------
__global__ __launch_bounds__(256, 2)
void k_gemm_gates(const float* __restrict__ A, const float* __restrict__ seqT,
                  const float* __restrict__ bias1, const float* __restrict__ bias2,
                  float* __restrict__ gatesT) {
  __shared__ float As[16][132];
  __shared__ float Bs[16][132];
  int tid = threadIdx.x;
  int tx = tid & 15, ty = tid >> 4;
  int n0 = blockIdx.x * 128, m0 = blockIdx.y * 128;
  int lr = tid >> 2;
  int lk = (tid & 3) * 4;
  int bkk = tid >> 4, bn8 = (tid & 15) * 8;
  float acc[8][8];
#pragma unroll
  for (int i = 0; i < 8; i++)
#pragma unroll
    for (int j = 0; j < 8; j++) acc[i][j] = 0.f;
  const float* Ab = A + (size_t)m0 * 512;
  for (int k0 = 0; k0 < 512; k0 += 16) {
    float4 a0 = *(const float4*)&Ab[(size_t)lr * 512 + k0 + lk];
    float4 a1 = *(const float4*)&Ab[(size_t)(lr + 64) * 512 + k0 + lk];
    const float* Bp = seqT + (size_t)(k0 + bkk) * 16384 + n0 + bn8;
    float4 b0 = *(const float4*)Bp;
    float4 b1 = *(const float4*)(Bp + 4);
    __syncthreads();
    As[lk + 0][lr] = a0.x; As[lk + 1][lr] = a0.y; As[lk + 2][lr] = a0.z; As[lk + 3][lr] = a0.w;
    As[lk + 0][lr + 64] = a1.x; As[lk + 1][lr + 64] = a1.y; As[lk + 2][lr + 64] = a1.z; As[lk + 3][lr + 64] = a1.w;
    *(float4*)&Bs[bkk][bn8] = b0;
    *(float4*)&Bs[bkk][bn8 + 4] = b1;
    __syncthreads();
#pragma unroll
    for (int kk = 0; kk < 16; kk++) {
      float4 av0 = *(const float4*)&As[kk][ty * 4];
      float4 av1 = *(const float4*)&As[kk][ty * 4 + 64];
      float4 bv0 = *(const float4*)&Bs[kk][tx * 4];
      float4 bv1 = *(const float4*)&Bs[kk][tx * 4 + 64];
      float am[8] = {av0.x, av0.y, av0.z, av0.w, av1.x, av1.y, av1.z, av1.w};
      float bn[8] = {bv0.x, bv0.y, bv0.z, bv0.w, bv1.x, bv1.y, bv1.z, bv1.w};
#pragma unroll
      for (int i = 0; i < 8; i++)
#pragma unroll
        for (int j = 0; j < 8; j++) acc[i][j] += am[i] * bn[j];
    }
  }
  int t0 = n0 >> 6;
#pragma unroll
  for (int i = 0; i < 8; i++) {
    int m = m0 + ((i < 4) ? (ty * 4 + i) : (64 + ty * 4 + (i - 4)));
    float bs = bias1[m] + bias2[m];
    float4 o0 = {acc[i][0] + bs, acc[i][1] + bs, acc[i][2] + bs, acc[i][3] + bs};
    float4 o1 = {acc[i][4] + bs, acc[i][5] + bs, acc[i][6] + bs, acc[i][7] + bs};
    *(float4*)&gatesT[((size_t)t0 * 2048 + m) * 64 + tx * 4] = o0;
    *(float4*)&gatesT[((size_t)(t0 + 1) * 2048 + m) * 64 + tx * 4] = o1;
  }
}

// ---------------- LSTM recurrence: rotating h-slots (L2-dedup), flag-vector barrier ----------------
// 128 WGs x 512 thr. WG=(d, 4 units). Thread=(b=tid&63, kq=wave 0..7 of 32-k slice).
// h published via sc-stores to slot tt+1 (write-through to MALL); consumed via NORMAL
// cached loads from slot tt (virgin addresses -> guaranteed miss -> per-XCD L2 dedup).
// Sync: per-WG flag store (sc) + wave-parallel sc poll; expect = layer*256+tt+1.
__global__ __launch_bounds__(512, 1)
void k_lstm_rec(const float* __restrict__ gatesT,   // [256][2048][64]
                const float* __restrict__ wPack,    // [128][256][16] this layer
                float* __restrict__ seqT_out,       // [512][16384]
                float* __restrict__ hrot,           // [257 slots][2 dir][256 u][64 b]
                int* __restrict__ flags,            // [2 dir][256 step][64 wg]
                int layer) {
  __shared__ float p_s[8 * 16 * 64];
  int wg = blockIdx.x, tid = threadIdx.x;
  int d = wg >> 6;
  int u0 = (wg & 63) * 4;
  int b = tid & 63;
  int kq = __builtin_amdgcn_readfirstlane(tid >> 6);   // wave index 0..7
  int uo = tid >> 6;                                   // pointwise role (tid<256)
  const float4* wp4 = (const float4*)(wPack + ((size_t)wg * 256 + kq * 32) * 16);
  float c = 0.f;

  for (int tt = 0; tt < 256; ++tt) {
    int t = d ? 255 - tt : tt;
    // prefetch this step's input-gate values (normal cached loads)
    float gin0 = 0.f, gin1 = 0.f, gin2 = 0.f, gin3 = 0.f;
    if (tid < 256) {
      const float* gp = gatesT + ((size_t)t * 2048 + d * 1024 + u0 + uo) * 64 + b;
      gin0 = gp[0 * 16384];
      gin1 = gp[1 * 16384];
      gin2 = gp[2 * 16384];
      gin3 = gp[3 * 16384];
    }
    // h slice for this wave: 32 coalesced NORMAL loads (slot tt is a virgin address:
    // guaranteed L2 miss -> MALL; 16 WGs/XCD share the L2 fill)
    const float* hcur = hrot + (size_t)tt * 32768 + (size_t)d * 16384 + kq * 2048 + b;
    float hreg[32];
#pragma unroll
    for (int j = 0; j < 32; j++) hreg[j] = hcur[j * 64];
    // GEMV: acc[rr] += wPack[k][rr] * h[k]; w chunks wave-uniform (scalar pipe)
    float acc[16];
#pragma unroll
    for (int r = 0; r < 16; r++) acc[r] = 0.f;
#pragma unroll 8
    for (int j = 0; j < 32; j++) {
      float hj = hreg[j];
      float4 w0 = wp4[j * 4 + 0];
      float4 w1 = wp4[j * 4 + 1];
      float4 w2 = wp4[j * 4 + 2];
      float4 w3 = wp4[j * 4 + 3];
      acc[0] += w0.x * hj;  acc[1] += w0.y * hj;  acc[2] += w0.z * hj;  acc[3] += w0.w * hj;
      acc[4] += w1.x * hj;  acc[5] += w1.y * hj;  acc[6] += w1.z * hj;  acc[7] += w1.w * hj;
      acc[8] += w2.x * hj;  acc[9] += w2.y * hj;  acc[10] += w2.z * hj; acc[11] += w2.w * hj;
      acc[12] += w3.x * hj; acc[13] += w3.y * hj; acc[14] += w3.z * hj; acc[15] += w3.w * hj;
    }
#pragma unroll
    for (int r = 0; r < 16; r++) p_s[(kq * 16 + r) * 64 + b] = acc[r];
    __syncthreads();
    // combine + pointwise + publish (tid<256; unit u0+uo, batch b)
    if (tid < 256) {
      float gv[4] = {gin0, gin1, gin2, gin3};
#pragma unroll
      for (int g = 0; g < 4; g++) {
        int rr = g * 4 + uo;
        float s = gv[g];
#pragma unroll
        for (int q = 0; q < 8; q++) s += p_s[(q * 16 + rr) * 64 + b];
        gv[g] = s;
      }
      c = sigmoidf_(gv[1]) * c + sigmoidf_(gv[0]) * tanhf(gv[2]);
      float h = sigmoidf_(gv[3]) * tanhf(c);
      if (tt < 255) {
        float* hnext = hrot + (size_t)(tt + 1) * 32768 + (size_t)d * 16384;
        st1_sc(hnext + (u0 + uo) * 64 + b, h);                        // write-through to MALL
      }
      seqT_out[(size_t)(d * 256 + u0 + uo) * 16384 + t * 64 + b] = h; // coalesced 256B/wave
    }
    if (tt < 255) {
      waitcnt0();            // drain own h-stores (at MALL when vmcnt==0)
      __syncthreads();       // all threads' stores drained
      if (tid < 64) {
        int* fbase = flags + d * 16384 + tt * 64;
        int expect = layer * 256 + tt + 1;
        if (tid == 0) sti_sc(fbase + (wg & 63), expect);
        while (true) {
          int v = ldi_sc(fbase + tid);
          waitcnt0();
          if (__all(v == expect)) break;
          __builtin_amdgcn_s_sleep(1);
        }
      }
      __syncthreads();
    }
  }
}

// ---------------- emissions: em[tb][tag] = sum_ch seqT[ch][tb]*owT[ch][tag] + out_b ----------------
__global__ __launch_bounds__(256, 4)
void k_emis(const float* __restrict__ seqT, const float* __restrict__ owT,
            const float* __restrict__ out_b, float* __restrict__ em) {
  int tb = blockIdx.x * 256 + threadIdx.x;   // 64 WGs
  float p[TAGS];
#pragma unroll
  for (int t = 0; t < TAGS; t++) p[t] = 0.f;
  for (int ch = 0; ch < 512; ch++) {
    float sv = seqT[(size_t)ch * 16384 + tb];
    const float4* o4 = (const float4*)(owT + ch * 12);   // wave-uniform -> scalar loads
    float4 oa = o4[0], ob = o4[1];
    float oc = owT[ch * 12 + 8];
    p[0] += sv * oa.x; p[1] += sv * oa.y; p[2] += sv * oa.z; p[3] += sv * oa.w;
    p[4] += sv * ob.x; p[5] += sv * ob.y; p[6] += sv * ob.z; p[7] += sv * ob.w;
    p[8] += sv * oc;
  }
#pragma unroll
  for (int t = 0; t < TAGS; t++) em[(size_t)tb * TAGS + t] = p[t] + out_b[t];
}

// ---------------- Viterbi: one wave per batch ----------------
__global__ void k_viterbi(const float* __restrict__ em, const float* __restrict__ start_t,
                          const float* __restrict__ end_t, const float* __restrict__ trans,
                          float* __restrict__ out) {
  int b = blockIdx.x;
  int lane = threadIdx.x;
  __shared__ unsigned char hist[255 * TAGS];
  float tin[TAGS];
#pragma unroll
  for (int p = 0; p < TAGS; p++) tin[p] = (lane < TAGS) ? trans[p * TAGS + lane] : 0.f;
  float score = -1e30f;
  if (lane < TAGS) score = start_t[lane] + em[(size_t)b * TAGS + lane];
  for (int t = 1; t < 256; t++) {
    float best = -1e30f; int bp = 0;
#pragma unroll
    for (int p = 0; p < TAGS; p++) {
      float v = __shfl(score, p, 64) + tin[p];
      if (v > best) { best = v; bp = p; }   // strict > + ascending p == first-max (jnp.argmax)
    }
    if (lane < TAGS) {
      score = best + em[(size_t)(t * 64 + b) * TAGS + lane];
      hist[(t - 1) * TAGS + lane] = (unsigned char)bp;
    }
  }
  float fin = (lane < TAGS) ? (score + end_t[lane]) : -1e30f;
  float bsc = -1e30f; int bl = 0;
#pragma unroll
  for (int p = 0; p < TAGS; p++) {
    float v = __shfl(fin, p, 64);
    if (v > bsc) { bsc = v; bl = p; }
  }
  __syncthreads();
  if (lane == 0) {
    out[(size_t)16384 + b] = bsc;
    int tag = bl;
    out[(size_t)b * 256 + 255] = (float)tag;
    for (int t = 254; t >= 0; t--) {
      tag = hist[t * TAGS + tag];
      out[(size_t)b * 256 + t] = (float)tag;
    }
  }
}

extern "C" void kernel_launch(void* const* d_in, const int* in_sizes, int n_in,
                              void* d_out, int out_size, void* d_ws, size_t ws_size,
                              hipStream_t stream) {
  const int*   x       = (const int*)d_in[0];
  const float* table   = (const float*)d_in[1];
  const float* w_ih    = (const float*)d_in[2];   // [2][2][1024][512]
  const float* w_hh    = (const float*)d_in[3];   // [2][2][1024][256]
  const float* b_ih    = (const float*)d_in[4];
  const float* b_hh    = (const float*)d_in[5];
  const float* out_w   = (const float*)d_in[6];
  const float* out_b   = (const float*)d_in[7];
  const float* start_t = (const float*)d_in[8];
  const float* end_t   = (const float*)d_in[9];
  const float* trans   = (const float*)d_in[10];
  float* out = (float*)d_out;
  float* ws = (float*)d_ws;

  float* seqT0  = ws;                       // 8,388,608  (embeds -> layer-1 output)
  float* seqT1  = seqT0 + 8388608;          // 8,388,608  (layer-0 output)
  float* gatesT = seqT1 + 8388608;          // 33,554,432
  float* em     = gatesT;                   // overlays gatesT (dead by k_emis time)
  float* hrot   = gatesT + 33554432;        // 257*32768 = 8,421,376 (rotating h slots)
  float* wPack  = hrot + 8421376;           // 1,048,576 ([2 layers][128][256][16])
  float* owT    = wPack + 1048576;          // 6,144
  int*   flags  = (int*)(owT + 6144);       // 32,768 ints ([2 dir][256][64])
  // total ~240 MB

  hipMemsetAsync(hrot, 0, 32768 * sizeof(float), stream);   // slot 0 zeros (both layers' h0)

  k_pack_w<<<4096, 256, 0, stream>>>(w_hh, wPack);
  k_pack_ow<<<18, 256, 0, stream>>>(out_w, owT);
  k_gatherT<<<256, 256, 0, stream>>>(x, table, seqT0);

  dim3 gg(128, 16);
  k_gemm_gates<<<gg, 256, 0, stream>>>(w_ih, seqT0, b_ih, b_hh, gatesT);
  k_lstm_rec<<<128, 512, 0, stream>>>(gatesT, wPack, seqT1, hrot, flags, 0);
  k_gemm_gates<<<gg, 256, 0, stream>>>(w_ih + 1048576, seqT1, b_ih + 2048, b_hh + 2048, gatesT);
  k_lstm_rec<<<128, 512, 0, stream>>>(gatesT, wPack + 524288, seqT0, hrot, flags, 1);
  k_emis<<<64, 256, 0, stream>>>(seqT0, owT, out_b, em);
  k_viterbi<<<64, 64, 0, stream>>>(em, start_t, end_t, trans, out);
}